// Round 7
// baseline (690.777 us; speedup 1.0000x reference)
//
#include <hip/hip_runtime.h>
#include <math.h>

typedef __attribute__((ext_vector_type(8))) short short8;
typedef __attribute__((ext_vector_type(4))) float floatx4;

#define TB 16
#define TS 512
#define TD 768
#define TH 12
#define TDH 64
#define TNCH 3

#define SCALE 0.03608439182435161f  // 1/sqrt(768)

#define LDA_S 40   // ushort stride: 32 k + 8 pad
#define LDB_S 36   // ushort stride: 32 k + 4 pad

__device__ __forceinline__ unsigned short f2bf(float f) {
  unsigned u = __float_as_uint(f);
  u += 0x7fffu + ((u >> 16) & 1u);   // round-to-nearest-even
  return (unsigned short)(u >> 16);
}
__device__ __forceinline__ unsigned f2bf2(float lo, float hi) {
  return (unsigned)f2bf(lo) | ((unsigned)f2bf(hi) << 16);
}

union U4 { uint4 u; short8 s; };

// ===================== prep kernels (one-shot convert/transpose) ============
__global__ __launch_bounds__(256)
void pconv(const float* __restrict__ src, unsigned short* __restrict__ dst) {
  const int i = (blockIdx.x * 256 + threadIdx.x) * 8;
  const float4 a = *(const float4*)&src[i];
  const float4 b = *(const float4*)&src[i + 4];
  uint4 o;
  o.x = f2bf2(a.x, a.y); o.y = f2bf2(a.z, a.w);
  o.z = f2bf2(b.x, b.y); o.w = f2bf2(b.z, b.w);
  *(uint4*)&dst[i] = o;
}

__global__ __launch_bounds__(256)
void ptrans(const float* __restrict__ src, unsigned short* __restrict__ dst,
            int R, int C) {
  __shared__ float ts[32][33];
  const size_t zoff = (size_t)blockIdx.z * R * C;
  src += zoff; dst += zoff;
  const int c0 = blockIdx.x * 32, r0 = blockIdx.y * 32;
  const int x = threadIdx.x & 31, y = threadIdx.x >> 5;
#pragma unroll
  for (int i = 0; i < 4; i++)
    ts[y + 8 * i][x] = src[(size_t)(r0 + y + 8 * i) * C + c0 + x];
  __syncthreads();
#pragma unroll
  for (int i = 0; i < 4; i++)
    dst[(size_t)(c0 + y + 8 * i) * R + r0 + x] = f2bf(ts[x][y + 8 * i]);
}

// ---- unified bf16 tile stage: src row-major [rows][ld], 128x32 tile ----
template <int DS>
__device__ __forceinline__ void stage_bf16(const unsigned short* __restrict__ S, int ld,
                                           int row0, int k0, int tid,
                                           unsigned short* D) {
#pragma unroll
  for (int i = 0; i < 2; i++) {
    const int idx = tid + i * 256;
    const int r = idx >> 2, g = idx & 3;
    const uint4 v = *(const uint4*)&S[(size_t)(row0 + r) * ld + k0 + g * 8];
    *(uint4*)&D[r * DS + g * 8] = v;
  }
}

__device__ __forceinline__ void mfma_step(const unsigned short* As, const unsigned short* Bs,
                                          int wy, int wx, int l16, int quad,
                                          floatx4 acc[4][4]) {
  short8 af[4], bfr[4];
#pragma unroll
  for (int i = 0; i < 4; i++) {
    U4 t; t.u = *(const uint4*)&As[(wy * 64 + i * 16 + l16) * LDA_S + quad * 8];
    af[i] = t.s;
  }
#pragma unroll
  for (int j = 0; j < 4; j++) {
    const unsigned short* bp = &Bs[(wx * 64 + j * 16 + l16) * LDB_S + quad * 8];
    uint2 lo = *(const uint2*)bp;
    uint2 hi = *(const uint2*)(bp + 4);
    U4 t; t.u = make_uint4(lo.x, lo.y, hi.x, hi.y);
    bfr[j] = t.s;
  }
#pragma unroll
  for (int i = 0; i < 4; i++)
#pragma unroll
    for (int j = 0; j < 4; j++)
      acc[i][j] = __builtin_amdgcn_mfma_f32_16x16x32_bf16(af[i], bfr[j], acc[i][j], 0, 0, 0);
}

// ===== K1: qk = Htb @ WqkT^T + b_qk -> Q,K (bf16), pure-bf16 staging =====
__global__ __launch_bounds__(256, 2)
void k1_qk(const unsigned short* __restrict__ Htb, const unsigned short* __restrict__ WqkT,
           const float* __restrict__ bias, unsigned short* __restrict__ Q,
           unsigned short* __restrict__ Ko) {
  __shared__ unsigned short As[128 * LDA_S];
  __shared__ unsigned short Bs[128 * LDB_S];
  const int tid = threadIdx.x;
  const int row0 = blockIdx.y * 128, col0 = blockIdx.x * 128;
  const int w = tid >> 6, lane = tid & 63;
  const int wy = w >> 1, wx = w & 1, l16 = lane & 15, quad = lane >> 4;
  floatx4 acc[4][4];
#pragma unroll
  for (int i = 0; i < 4; i++)
#pragma unroll
    for (int j = 0; j < 4; j++)
#pragma unroll
      for (int r = 0; r < 4; r++) acc[i][j][r] = 0.f;

  for (int k0 = 0; k0 < TD; k0 += 32) {
    stage_bf16<LDA_S>(Htb, TD, row0, k0, tid, As);
    stage_bf16<LDB_S>(WqkT, TD, col0, k0, tid, Bs);
    __syncthreads();
    mfma_step(As, Bs, wy, wx, l16, quad, acc);
    __syncthreads();
  }
#pragma unroll
  for (int i = 0; i < 4; i++)
#pragma unroll
    for (int j = 0; j < 4; j++) {
      const int col = col0 + wx * 64 + j * 16 + l16;
      const float bs = bias[col];
#pragma unroll
      for (int r = 0; r < 4; r++) {
        const int row = row0 + wy * 64 + i * 16 + quad * 4 + r;
        const float v = acc[i][j][r] + bs;
        if (col < TD) Q[(size_t)row * TD + col] = f2bf(v);
        else          Ko[(size_t)row * TD + (col - TD)] = f2bf(v);
      }
    }
}

// ==== K2: one channel per block; fp32 M in registers, read once ====
// Grid 1536: xcd=i0&7, b=xcd+8*(t&1), ch fastest in rest (3 ch blocks of the
// same (b,q0) share Q/K lines in L2). Wave w owns k-quarter w*128.
#define OB_S 520
__global__ __launch_bounds__(256, 4)
void k2_attn(const unsigned short* __restrict__ Q, const unsigned short* __restrict__ Kb,
             const float* __restrict__ Ml, const float* __restrict__ am,
             unsigned short* __restrict__ Am) {
  __shared__ float smx[16][4];
  __shared__ float2 szd[16][4];
  __shared__ unsigned short obuf[16 * OB_S];
  const int i0 = blockIdx.x;
  const int xcd = i0 & 7, t = i0 >> 3;       // t in [0,192)
  const int b = xcd + 8 * (t & 1);
  const int rest = t >> 1;                   // [0,96)
  const int ch = rest % 3;
  const int q0 = (rest / 3) * 16;
  const int tid = threadIdx.x;
  const int w = tid >> 6, lane = tid & 63;
  const int l16 = lane & 15, quad = lane >> 4;
  const int kbase = w * 128;

  const float* amb = am + b * TS;
  float amq[4], amk[8], maskv[8];
#pragma unroll
  for (int r = 0; r < 4; r++) amq[r] = amb[q0 + quad * 4 + r];
#pragma unroll
  for (int kt = 0; kt < 8; kt++) {
    amk[kt] = amb[kbase + kt * 16 + l16];
    maskv[kt] = (1.f - amk[kt]) * (-1e9f);
  }

  // masked fp32 M, registers, read ONCE (channel ch only)
  float Mf[4][8];
#pragma unroll
  for (int r = 0; r < 4; r++) {
    const float* Mrow = Ml + ((size_t)((b * TNCH + ch) * TS + q0 + quad * 4 + r)) * TS;
#pragma unroll
    for (int kt = 0; kt < 8; kt++)
      Mf[r][kt] = Mrow[kbase + kt * 16 + l16] * amk[kt] * amq[r];
  }

  float acc[8][4];
#pragma unroll
  for (int kt = 0; kt < 8; kt++)
#pragma unroll
    for (int r = 0; r < 4; r++) acc[kt][r] = 0.f;

  const unsigned short* qbase = Q + ((size_t)(b * TS + q0 + l16)) * TD + quad * 8;
  const unsigned short* kb0   = Kb + ((size_t)(b * TS + kbase + l16)) * TD + quad * 8;

  for (int h = 0; h < TH; h++) {
    floatx4 sacc[8];
#pragma unroll
    for (int kt = 0; kt < 8; kt++)
#pragma unroll
      for (int r = 0; r < 4; r++) sacc[kt][r] = 0.f;
#pragma unroll
    for (int dk = 0; dk < 2; dk++) {
      U4 a; a.u = *(const uint4*)(qbase + h * TDH + dk * 32);
#pragma unroll
      for (int kt = 0; kt < 8; kt++) {
        U4 bb; bb.u = *(const uint4*)(kb0 + (size_t)kt * 16 * TD + h * TDH + dk * 32);
        sacc[kt] = __builtin_amdgcn_mfma_f32_16x16x32_bf16(a.s, bb.s, sacc[kt], 0, 0, 0);
      }
    }
    float s[8][4];
#pragma unroll
    for (int kt = 0; kt < 8; kt++)
#pragma unroll
      for (int r = 0; r < 4; r++) s[kt][r] = sacc[kt][r] * SCALE + maskv[kt];

    // row max: intra-quad-group shfl, then cross-wave via LDS
    float mxp[4];
#pragma unroll
    for (int r = 0; r < 4; r++) {
      float m = s[0][r];
#pragma unroll
      for (int kt = 1; kt < 8; kt++) m = fmaxf(m, s[kt][r]);
#pragma unroll
      for (int off = 1; off < 16; off <<= 1) m = fmaxf(m, __shfl_xor(m, off));
      mxp[r] = m;
    }
    if (l16 == 0) {
#pragma unroll
      for (int r = 0; r < 4; r++) smx[quad * 4 + r][w] = mxp[r];
    }
    __syncthreads();
    float mxg[4];
#pragma unroll
    for (int r = 0; r < 4; r++) {
      float4 tt = *(const float4*)smx[quad * 4 + r];
      mxg[r] = fmaxf(fmaxf(tt.x, tt.y), fmaxf(tt.z, tt.w));
    }

    float Zp[4] = {0.f, 0.f, 0.f, 0.f};
    float dmp[4] = {0.f, 0.f, 0.f, 0.f};
#pragma unroll
    for (int kt = 0; kt < 8; kt++)
#pragma unroll
      for (int r = 0; r < 4; r++) {
        const float e = __expf(s[kt][r] - mxg[r]);
        s[kt][r] = e;
        Zp[r] += e;
        dmp[r] += Mf[r][kt] * e;
      }
#pragma unroll
    for (int r = 0; r < 4; r++) {
#pragma unroll
      for (int off = 1; off < 16; off <<= 1) {
        Zp[r] += __shfl_xor(Zp[r], off);
        dmp[r] += __shfl_xor(dmp[r], off);
      }
    }
    if (l16 == 0) {
#pragma unroll
      for (int r = 0; r < 4; r++)
        szd[quad * 4 + r][w] = make_float2(Zp[r], dmp[r]);
    }
    __syncthreads();
#pragma unroll
    for (int r = 0; r < 4; r++) {
      const float2 t0 = szd[quad * 4 + r][0];
      const float2 t1 = szd[quad * 4 + r][1];
      const float2 t2 = szd[quad * 4 + r][2];
      const float2 t3 = szd[quad * 4 + r][3];
      const float Z  = t0.x + t1.x + t2.x + t3.x;
      const float winv = 1.f / (t0.y + t1.y + t2.y + t3.y + 1e-10f * Z);
#pragma unroll
      for (int kt = 0; kt < 8; kt++)
        acc[kt][r] += s[kt][r] * winv;
    }
  }

  // ---- epilogue: M from registers (fp32), obuf repack, 1-KB row stores ----
  const float inv_h = 1.f / (float)TH;
#pragma unroll
  for (int r = 0; r < 4; r++) {
#pragma unroll
    for (int kt = 0; kt < 8; kt++) {
      const int k = kbase + kt * 16 + l16;
      obuf[(quad * 4 + r) * OB_S + k] = f2bf(Mf[r][kt] * acc[kt][r] * inv_h);
    }
  }
  __syncthreads();
#pragma unroll
  for (int it = 0; it < 4; it++) {
    const int idx = tid + it * 256;            // 0..1023 = 16 rows x 64 uint4
    const int row = idx >> 6, c16 = idx & 63;
    const uint4 v = *(const uint4*)&obuf[row * OB_S + c16 * 8];
    *(uint4*)&Am[((size_t)((ch * TB + b) * TS + q0 + row)) * TS + c16 * 8] = v;
  }
}

// ===== K3: G[z] = Am[z] @ HtbT[b]^T -> bf16, pure-bf16 staging =====
__global__ __launch_bounds__(256, 2)
void k3_feat(const unsigned short* __restrict__ Am, const unsigned short* __restrict__ HtbT,
             unsigned short* __restrict__ G) {
  __shared__ unsigned short As[128 * LDA_S];
  __shared__ unsigned short Bs[128 * LDB_S];
  const int z = blockIdx.z;
  const int b = z & 15;
  const unsigned short* A  = Am + (size_t)z * TS * TS;
  const unsigned short* Bt = HtbT + (size_t)b * TD * TS;
  unsigned short* C = G + (size_t)z * TS * TD;
  const int tid = threadIdx.x;
  const int row0 = blockIdx.y * 128, col0 = blockIdx.x * 128;
  const int w = tid >> 6, lane = tid & 63;
  const int wy = w >> 1, wx = w & 1, l16 = lane & 15, quad = lane >> 4;
  floatx4 acc[4][4];
#pragma unroll
  for (int i = 0; i < 4; i++)
#pragma unroll
    for (int j = 0; j < 4; j++)
#pragma unroll
      for (int r = 0; r < 4; r++) acc[i][j][r] = 0.f;

  for (int k0 = 0; k0 < TS; k0 += 32) {
    stage_bf16<LDA_S>(A, TS, row0, k0, tid, As);
    stage_bf16<LDB_S>(Bt, TS, col0, k0, tid, Bs);
    __syncthreads();
    mfma_step(As, Bs, wy, wx, l16, quad, acc);
    __syncthreads();
  }
#pragma unroll
  for (int i = 0; i < 4; i++)
#pragma unroll
    for (int j = 0; j < 4; j++) {
      const int col = col0 + wx * 64 + j * 16 + l16;
#pragma unroll
      for (int r = 0; r < 4; r++) {
        const int row = row0 + wy * 64 + i * 16 + quad * 4 + r;
        C[(size_t)row * TD + col] = f2bf(acc[i][j][r]);
      }
    }
}

// == K4: out = mean_ch relu(G_ch @ WgT_ch^T + bg_ch) * am, pure-bf16 staging ==
__global__ __launch_bounds__(256, 2)
void k4_out(const unsigned short* __restrict__ G, const unsigned short* __restrict__ WgT,
            const float* __restrict__ bg, const float* __restrict__ am,
            float* __restrict__ out) {
  __shared__ unsigned short As[128 * LDA_S];
  __shared__ unsigned short Bs[128 * LDB_S];
  const int tid = threadIdx.x;
  const int row0 = blockIdx.y * 128, col0 = blockIdx.x * 128;
  const int w = tid >> 6, lane = tid & 63;
  const int wy = w >> 1, wx = w & 1, l16 = lane & 15, quad = lane >> 4;
  float osum[4][4][4];
#pragma unroll
  for (int i = 0; i < 4; i++)
#pragma unroll
    for (int j = 0; j < 4; j++)
#pragma unroll
      for (int r = 0; r < 4; r++) osum[i][j][r] = 0.f;

  for (int ch = 0; ch < TNCH; ch++) {
    const unsigned short* A  = G + (size_t)ch * (TB * TS) * TD;
    const unsigned short* Bt = WgT + (size_t)ch * TD * TD;
    floatx4 acc[4][4];
#pragma unroll
    for (int i = 0; i < 4; i++)
#pragma unroll
      for (int j = 0; j < 4; j++)
#pragma unroll
        for (int r = 0; r < 4; r++) acc[i][j][r] = 0.f;

    for (int k0 = 0; k0 < TD; k0 += 32) {
      stage_bf16<LDA_S>(A, TD, row0, k0, tid, As);
      stage_bf16<LDB_S>(Bt, TD, col0, k0, tid, Bs);
      __syncthreads();
      mfma_step(As, Bs, wy, wx, l16, quad, acc);
      __syncthreads();
    }
#pragma unroll
    for (int i = 0; i < 4; i++)
#pragma unroll
      for (int j = 0; j < 4; j++) {
        const int col = col0 + wx * 64 + j * 16 + l16;
        const float bs = bg[ch * TD + col];
#pragma unroll
        for (int r = 0; r < 4; r++)
          osum[i][j][r] += fmaxf(acc[i][j][r] + bs, 0.f);
      }
  }
#pragma unroll
  for (int i = 0; i < 4; i++)
#pragma unroll
    for (int r = 0; r < 4; r++) {
      const int row = row0 + wy * 64 + i * 16 + quad * 4 + r;
      const float amr = am[row] * (1.f / 3.f);
#pragma unroll
      for (int j = 0; j < 4; j++) {
        const int col = col0 + wx * 64 + j * 16 + l16;
        out[(size_t)row * TD + col] = osum[i][j][r] * amr;
      }
    }
}

extern "C" void kernel_launch(void* const* d_in, const int* in_sizes, int n_in,
                              void* d_out, int out_size, void* d_ws, size_t ws_size,
                              hipStream_t stream) {
  const float* Ht    = (const float*)d_in[0];
  const float* Ml    = (const float*)d_in[1];
  const float* am    = (const float*)d_in[2];
  const float* W_qk  = (const float*)d_in[3];
  const float* b_qk  = (const float*)d_in[4];
  const float* W_gat = (const float*)d_in[5];
  const float* b_gat = (const float*)d_in[6];
  float* out = (float*)d_out;

  unsigned short* base = (unsigned short*)d_ws;
  const size_t SEG = (size_t)TB * TS * TD;            // 6291456
  unsigned short* Q    = base;
  unsigned short* Kw   = base + SEG;
  unsigned short* Htb  = base + 2 * SEG;
  unsigned short* HtbT = base + 3 * SEG;
  unsigned short* WqkT = base + 4 * SEG;
  unsigned short* WgT  = WqkT + (size_t)TD * 2 * TD;
  unsigned short* Am   = WgT + (size_t)TNCH * TD * TD;
  unsigned short* G    = base;

  pconv <<<dim3(3072), 256, 0, stream>>>(Ht, Htb);
  ptrans<<<dim3(24, 16, 16), 256, 0, stream>>>(Ht, HtbT, TS, TD);
  ptrans<<<dim3(48, 24, 1),  256, 0, stream>>>(W_qk, WqkT, TD, 2 * TD);
  ptrans<<<dim3(24, 24, 3),  256, 0, stream>>>(W_gat, WgT, TD, TD);

  k1_qk  <<<dim3(12, 64), 256, 0, stream>>>(Htb, WqkT, b_qk, Q, Kw);
  k2_attn<<<dim3(1536), 256, 0, stream>>>(Q, Kw, Ml, am, Am);
  k3_feat<<<dim3(6, 4, 48), 256, 0, stream>>>(Am, HtbT, G);
  k4_out <<<dim3(6, 64), 256, 0, stream>>>(G, WgT, b_gat, am, out);
}